// Round 4
// baseline (570.316 us; speedup 1.0000x reference)
//
#include <hip/hip_runtime.h>

// CBAM attention, fp32 in/out. B=32, C=512, Cr=64, H=W=64, HW=4096.
// R4: conv_out uses cached x-loads (LLC-resident after scale_pool) + NT
// stores only; scale_pool re-tiled to 2048 blocks / 8 per CU (32 ch/thread).

#define B_   32
#define C_   512
#define CR_  64
#define HW_  4096
#define WID_ 64
#define EPSF 1e-12f

typedef float f32x4 __attribute__((ext_vector_type(4)));

__device__ __forceinline__ float sigmoidf(float x) {
  return 1.0f / (1.0f + __expf(-x));
}

// ---------------- K1: avg/max over HW, one wave per (b,c) plane ----------------
__global__ __launch_bounds__(256) void pool_kernel(const float* __restrict__ x,
                                                   float* __restrict__ avg,
                                                   float* __restrict__ mx) {
  const int plane = blockIdx.x * 4 + (threadIdx.x >> 6);  // 4 waves = 4 planes
  const int lane = threadIdx.x & 63;
  const float4* xp = (const float4*)(x + (size_t)plane * HW_);
  float s = 0.0f, m = -INFINITY;
  #pragma unroll
  for (int q = 0; q < 16; q++) {
    float4 a = xp[q * 64 + lane];
    s += (a.x + a.y) + (a.z + a.w);
    m = fmaxf(m, fmaxf(fmaxf(a.x, a.y), fmaxf(a.z, a.w)));
  }
  #pragma unroll
  for (int o = 32; o > 0; o >>= 1) {
    s += __shfl_down(s, o);
    m = fmaxf(m, __shfl_down(m, o));
  }
  if (lane == 0) {
    avg[plane] = s * (1.0f / HW_);
    mx[plane] = m;
  }
}

// ---------------- K2: sv1 || sv2 (wave-group parallel) + MLP -> s[B,C] ----------------
// grid: dim3(4, B_): blockIdx.x = output quarter, blockIdx.y = b
__global__ __launch_bounds__(256) void mlp_kernel(const float* __restrict__ avg, const float* __restrict__ mx,
                                                  const float* __restrict__ w1, const float* __restrict__ b1,
                                                  const float* __restrict__ u1,
                                                  const float* __restrict__ w2, const float* __restrict__ b2,
                                                  const float* __restrict__ u2,
                                                  float* __restrict__ s) {
  const int b = blockIdx.y;
  const int qtr = blockIdx.x;
  const int t = threadIdx.x;
  __shared__ float v1[C_];
  __shared__ float v2[CR_];
  __shared__ float red[256];
  __shared__ float part2[128];
  __shared__ float u1s[CR_];
  __shared__ float u2s[C_];
  __shared__ float pool2[2][C_];
  __shared__ float hid[2][CR_];

  // phase 0: stage all small vectors
  if (t < CR_) u1s[t] = u1[t];
  for (int i = t; i < C_; i += 256) {
    u2s[i] = u2[i];
    pool2[0][i] = avg[b * C_ + i];
    pool2[1][i] = mx[b * C_ + i];
  }
  __syncthreads();

  // phase A: g0 (t<128) computes v1 = u1 @ W1m; g1 computes v2 = u2 @ W2m partials
  float sqp = 0.0f;
  if (t < 128) {
    const int j0 = t * 4;
    float a0 = 0.f, a1 = 0.f, a2 = 0.f, a3 = 0.f;
    #pragma unroll 8
    for (int i = 0; i < CR_; i++) {
      float ui = u1s[i];
      float4 wv = *(const float4*)(w1 + (size_t)i * C_ + j0);
      a0 += ui * wv.x; a1 += ui * wv.y; a2 += ui * wv.z; a3 += ui * wv.w;
    }
    v1[j0] = a0; v1[j0 + 1] = a1; v1[j0 + 2] = a2; v1[j0 + 3] = a3;
    sqp = a0 * a0 + a1 * a1 + a2 * a2 + a3 * a3;
  } else {
    const int tt = t - 128, j = tt & 63, half = tt >> 6;
    const float* wp = w2 + (size_t)(half * 256) * CR_ + j;
    float a = 0.0f;
    #pragma unroll 8
    for (int i = 0; i < 256; i++) a += u2s[half * 256 + i] * wp[(size_t)i * CR_];
    part2[tt] = a;
  }
  __syncthreads();
  if (t >= 128) {
    const int tt = t - 128;
    if (tt < CR_) { float vv = part2[tt] + part2[tt + 64]; v2[tt] = vv; sqp = vv * vv; }
  }
  red[t] = sqp;
  __syncthreads();
  const int rbase = t & 128, ridx = t & 127;
  #pragma unroll
  for (int o = 64; o > 0; o >>= 1) {
    if (ridx < o) red[rbase + ridx] += red[rbase + ridx + o];
    __syncthreads();
  }
  const float dv1 = fmaxf(sqrtf(red[0]), EPSF);
  const float dv2 = fmaxf(sqrtf(red[128]), EPSF);
  __syncthreads();

  // phase C: g0: a1_i = (v1/dv1) @ W1m.T; g1: a2_i = (v2/dv2) @ W2m.T
  float sq2 = 0.0f;
  if (t < 128) {
    const int i = t >> 1, part = t & 1;
    const float4* wr = (const float4*)(w1 + (size_t)i * C_ + part * 256);
    float acc = 0.0f;
    #pragma unroll 8
    for (int q = 0; q < 64; q++) {
      float4 wv = wr[q];
      int j = part * 256 + 4 * q;
      acc += v1[j] * wv.x + v1[j + 1] * wv.y + v1[j + 2] * wv.z + v1[j + 3] * wv.w;
    }
    acc += __shfl_down(acc, 1);
    if (part == 0) { float a2 = acc / dv1; sq2 = a2 * a2; }
  } else {
    const int tt = t - 128;
    #pragma unroll
    for (int r = 0; r < 4; r++) {
      const int i = tt * 4 + r;
      const float4* wr = (const float4*)(w2 + (size_t)i * CR_);
      float acc = 0.0f;
      #pragma unroll
      for (int q = 0; q < 16; q++) {
        float4 wv = wr[q];
        acc += v2[4 * q] * wv.x + v2[4 * q + 1] * wv.y +
               v2[4 * q + 2] * wv.z + v2[4 * q + 3] * wv.w;
      }
      acc /= dv2;
      sq2 += acc * acc;
    }
  }
  red[t] = sq2;
  __syncthreads();
  #pragma unroll
  for (int o = 64; o > 0; o >>= 1) {
    if (ridx < o) red[rbase + ridx] += red[rbase + ridx + o];
    __syncthreads();
  }
  const float nt1 = red[0], nt2 = red[128];
  const float inv1 = fmaxf(sqrtf(nt1), EPSF) / nt1;   // 1/sv1
  const float inv2 = fmaxf(sqrtf(nt2), EPSF) / nt2;   // 1/sv2
  __syncthreads();

  // phase E: MLP
  if (t < 2 * CR_) {
    const int kind = t >> 6, i = t & 63;
    const float4* wr = (const float4*)(w1 + (size_t)i * C_);
    float acc = 0.0f;
    #pragma unroll 8
    for (int qq = 0; qq < C_ / 4; qq++) {
      float4 u = wr[qq];
      acc += pool2[kind][qq * 4 + 0] * u.x + pool2[kind][qq * 4 + 1] * u.y +
             pool2[kind][qq * 4 + 2] * u.z + pool2[kind][qq * 4 + 3] * u.w;
    }
    hid[kind][i] = fmaxf(acc * inv1 + b1[i], 0.0f);
  }
  __syncthreads();
  if (t < 128) {
    const int c = qtr * 128 + t;
    const float4* wr = (const float4*)(w2 + (size_t)c * CR_);
    float aa = 0.0f, mm = 0.0f;
    #pragma unroll
    for (int k = 0; k < 16; k++) {
      float4 wv = wr[k];
      aa += hid[0][4 * k] * wv.x + hid[0][4 * k + 1] * wv.y +
            hid[0][4 * k + 2] * wv.z + hid[0][4 * k + 3] * wv.w;
      mm += hid[1][4 * k] * wv.x + hid[1][4 * k + 1] * wv.y +
            hid[1][4 * k + 2] * wv.z + hid[1][4 * k + 3] * wv.w;
    }
    float val = (aa + mm) * inv2 + 2.0f * b2[c];
    s[b * C_ + c] = sigmoidf(val);
  }
}

// ---------------- K3: x*s, mean/max over C -> ca, cm ----------------
// grid dim3(64, B_), 256 thr: 16 c-groups x 16 px-slots; 4 px float4/thread
__global__ __launch_bounds__(256) void scale_pool_kernel(const float* __restrict__ x,
                                                         const float* __restrict__ s,
                                                         float* __restrict__ ca,
                                                         float* __restrict__ cm) {
  const int b = blockIdx.y;
  const int hw0 = blockIdx.x * 64;
  const int t = threadIdx.x;
  const int pxs = t & 15;             // 16 slots * 4 px = 64 px
  const int cg = t >> 4;              // 16 groups * 32 channels
  __shared__ float srow[C_];
  for (int i = t; i < C_; i += 256) srow[i] = s[b * C_ + i];
  __syncthreads();
  const int px = hw0 + pxs * 4;
  const float* xb = x + (size_t)b * C_ * HW_ + px;
  float4 sm = make_float4(0.f, 0.f, 0.f, 0.f);
  float4 mxv = make_float4(-INFINITY, -INFINITY, -INFINITY, -INFINITY);
  const int c0 = cg * 32;
  #pragma unroll 8
  for (int c = c0; c < c0 + 32; c++) {
    float4 u = *(const float4*)(xb + (size_t)c * HW_);
    float sc = srow[c];
    float v0 = u.x * sc, v1 = u.y * sc, v2 = u.z * sc, v3 = u.w * sc;
    sm.x += v0; sm.y += v1; sm.z += v2; sm.w += v3;
    mxv.x = fmaxf(mxv.x, v0); mxv.y = fmaxf(mxv.y, v1);
    mxv.z = fmaxf(mxv.z, v2); mxv.w = fmaxf(mxv.w, v3);
  }
  __shared__ float4 rs[16][16], rm[16][16];  // 8 KB
  rs[cg][pxs] = sm; rm[cg][pxs] = mxv;
  __syncthreads();
  if (t < 16) {
    float4 S = rs[0][t], M = rm[0][t];
    #pragma unroll
    for (int g = 1; g < 16; g++) {
      float4 a = rs[g][t], m2 = rm[g][t];
      S.x += a.x; S.y += a.y; S.z += a.z; S.w += a.w;
      M.x = fmaxf(M.x, m2.x); M.y = fmaxf(M.y, m2.y);
      M.z = fmaxf(M.z, m2.z); M.w = fmaxf(M.w, m2.w);
    }
    S.x *= (1.0f / C_); S.y *= (1.0f / C_); S.z *= (1.0f / C_); S.w *= (1.0f / C_);
    *(float4*)(ca + (size_t)b * HW_ + hw0 + t * 4) = S;
    *(float4*)(cm + (size_t)b * HW_ + hw0 + t * 4) = M;
  }
}

// ---------------- K4: conv(3x3, sv3) -> sy in LDS; out = x*s*sy ----------------
// grid dim3(32, B_), 256 thr; block owns 128 px x all 512 channels.
// x loads CACHED (LLC-resident from scale_pool pass); out stores NT.
__global__ __launch_bounds__(256) void conv_out_kernel(const float* __restrict__ x,
                                                       const float* __restrict__ s,
                                                       const float* __restrict__ ca,
                                                       const float* __restrict__ cm,
                                                       const float* __restrict__ w3,
                                                       const float* __restrict__ b3,
                                                       const float* __restrict__ u3,
                                                       float* __restrict__ out) {
  const int b = blockIdx.y;
  const int hw0 = blockIdx.x * 128;
  const int t = threadIdx.x;
  __shared__ float srow[C_];
  __shared__ __align__(16) float syt[128];
  __shared__ float wns[18];
  __shared__ float b3s;
  if (t == 0) {
    float u3v = u3[0];
    float nvs = 0.0f;
    for (int k = 0; k < 18; k++) { float vv = u3v * w3[k]; nvs += vv * vv; }
    float d = fmaxf(sqrtf(nvs), EPSF);
    float tt = 0.0f;
    for (int k = 0; k < 18; k++) tt += (u3v * w3[k] / d) * w3[k];
    float u2n = tt / fmaxf(fabsf(tt), EPSF);
    float inv3 = 1.0f / (tt * u2n);
    for (int k = 0; k < 18; k++) wns[k] = w3[k] * inv3;
    b3s = b3[0];
  }
  for (int i = t; i < C_; i += 256) srow[i] = s[b * C_ + i];
  __syncthreads();
  if (t < 128) {
    const int px = hw0 + t;
    const int h = px >> 6, w = px & 63;
    float acc = b3s;
    #pragma unroll
    for (int dh = -1; dh <= 1; dh++) {
      int hh = h + dh;
      if (hh < 0 || hh >= 64) continue;
      #pragma unroll
      for (int dw = -1; dw <= 1; dw++) {
        int ww = w + dw;
        if (ww < 0 || ww >= WID_) continue;
        int n = b * HW_ + hh * WID_ + ww;
        int k = (dh + 1) * 3 + (dw + 1);
        acc += ca[n] * wns[k] + cm[n] * wns[9 + k];
      }
    }
    syt[t] = sigmoidf(acc);
  }
  __syncthreads();
  // phase 2: stream all channels; cached reads, NT writes
  const int pxs = t & 31;             // 32 slots * 4 px
  const int cg = t >> 5;              // 8 groups * 64 channels
  const f32x4 sy4 = *(const f32x4*)(&syt[pxs * 4]);
  const size_t base = (size_t)b * C_ * HW_ + hw0 + pxs * 4;
  const int c0 = cg * 64;
  #pragma unroll 8
  for (int c = c0; c < c0 + 64; c++) {
    const f32x4 u = *(const f32x4*)(x + base + (size_t)c * HW_);
    const f32x4 r = u * (srow[c] * sy4);
    __builtin_nontemporal_store(r, (f32x4*)(out + base + (size_t)c * HW_));
  }
}

extern "C" void kernel_launch(void* const* d_in, const int* in_sizes, int n_in,
                              void* d_out, int out_size, void* d_ws, size_t ws_size,
                              hipStream_t stream) {
  const float* x  = (const float*)d_in[0];
  const float* w1 = (const float*)d_in[1];
  const float* b1 = (const float*)d_in[2];
  const float* u1 = (const float*)d_in[3];
  const float* w2 = (const float*)d_in[4];
  const float* b2 = (const float*)d_in[5];
  const float* u2 = (const float*)d_in[6];
  const float* w3 = (const float*)d_in[7];
  const float* b3 = (const float*)d_in[8];
  const float* u3 = (const float*)d_in[9];

  float* ws = (float*)d_ws;
  float* avg = ws;                    // 16384 floats
  float* mx  = ws + 16384;            // 16384
  float* s   = ws + 32768;            // 16384
  float* ca  = ws + 49152;            // 131072
  float* cm  = ws + 180224;           // 131072  (total ~1.2 MiB)

  pool_kernel<<<B_ * C_ / 4, 256, 0, stream>>>(x, avg, mx);
  mlp_kernel<<<dim3(4, B_), 256, 0, stream>>>(avg, mx, w1, b1, u1, w2, b2, u2, s);
  scale_pool_kernel<<<dim3(64, B_), 256, 0, stream>>>(x, s, ca, cm);
  conv_out_kernel<<<dim3(32, B_), 256, 0, stream>>>(x, s, ca, cm, w3, b3, u3, (float*)d_out);
}

// Round 5
// 566.979 us; speedup vs baseline: 1.0059x; 1.0059x over previous
//
#include <hip/hip_runtime.h>

// CBAM attention, fp32 in/out. B=32, C=512, Cr=64, H=W=64, HW=4096.
// R5: scale_pool & conv_out re-mapped so each WAVE reads 1 KB contiguous
// per channel (lane = px-slot, wave = channel group); 1024-thr blocks,
// 256-px tiles, 512 blocks (2/CU, 32 waves/CU).

#define B_   32
#define C_   512
#define CR_  64
#define HW_  4096
#define WID_ 64
#define EPSF 1e-12f

typedef float f32x4 __attribute__((ext_vector_type(4)));

__device__ __forceinline__ float sigmoidf(float x) {
  return 1.0f / (1.0f + __expf(-x));
}

// ---------------- K1: avg/max over HW, one wave per (b,c) plane ----------------
__global__ __launch_bounds__(256) void pool_kernel(const float* __restrict__ x,
                                                   float* __restrict__ avg,
                                                   float* __restrict__ mx) {
  const int plane = blockIdx.x * 4 + (threadIdx.x >> 6);  // 4 waves = 4 planes
  const int lane = threadIdx.x & 63;
  const float4* xp = (const float4*)(x + (size_t)plane * HW_);
  float s = 0.0f, m = -INFINITY;
  #pragma unroll
  for (int q = 0; q < 16; q++) {
    float4 a = xp[q * 64 + lane];
    s += (a.x + a.y) + (a.z + a.w);
    m = fmaxf(m, fmaxf(fmaxf(a.x, a.y), fmaxf(a.z, a.w)));
  }
  #pragma unroll
  for (int o = 32; o > 0; o >>= 1) {
    s += __shfl_down(s, o);
    m = fmaxf(m, __shfl_down(m, o));
  }
  if (lane == 0) {
    avg[plane] = s * (1.0f / HW_);
    mx[plane] = m;
  }
}

// ---------------- K2: sv1 || sv2 (wave-group parallel) + MLP -> s[B,C] ----------------
// grid: dim3(4, B_): blockIdx.x = output quarter, blockIdx.y = b
__global__ __launch_bounds__(256) void mlp_kernel(const float* __restrict__ avg, const float* __restrict__ mx,
                                                  const float* __restrict__ w1, const float* __restrict__ b1,
                                                  const float* __restrict__ u1,
                                                  const float* __restrict__ w2, const float* __restrict__ b2,
                                                  const float* __restrict__ u2,
                                                  float* __restrict__ s) {
  const int b = blockIdx.y;
  const int qtr = blockIdx.x;
  const int t = threadIdx.x;
  __shared__ float v1[C_];
  __shared__ float v2[CR_];
  __shared__ float red[256];
  __shared__ float part2[128];
  __shared__ float u1s[CR_];
  __shared__ float u2s[C_];
  __shared__ float pool2[2][C_];
  __shared__ float hid[2][CR_];

  // phase 0: stage all small vectors
  if (t < CR_) u1s[t] = u1[t];
  for (int i = t; i < C_; i += 256) {
    u2s[i] = u2[i];
    pool2[0][i] = avg[b * C_ + i];
    pool2[1][i] = mx[b * C_ + i];
  }
  __syncthreads();

  // phase A: g0 (t<128) computes v1 = u1 @ W1m; g1 computes v2 = u2 @ W2m partials
  float sqp = 0.0f;
  if (t < 128) {
    const int j0 = t * 4;
    float a0 = 0.f, a1 = 0.f, a2 = 0.f, a3 = 0.f;
    #pragma unroll 8
    for (int i = 0; i < CR_; i++) {
      float ui = u1s[i];
      float4 wv = *(const float4*)(w1 + (size_t)i * C_ + j0);
      a0 += ui * wv.x; a1 += ui * wv.y; a2 += ui * wv.z; a3 += ui * wv.w;
    }
    v1[j0] = a0; v1[j0 + 1] = a1; v1[j0 + 2] = a2; v1[j0 + 3] = a3;
    sqp = a0 * a0 + a1 * a1 + a2 * a2 + a3 * a3;
  } else {
    const int tt = t - 128, j = tt & 63, half = tt >> 6;
    const float* wp = w2 + (size_t)(half * 256) * CR_ + j;
    float a = 0.0f;
    #pragma unroll 8
    for (int i = 0; i < 256; i++) a += u2s[half * 256 + i] * wp[(size_t)i * CR_];
    part2[tt] = a;
  }
  __syncthreads();
  if (t >= 128) {
    const int tt = t - 128;
    if (tt < CR_) { float vv = part2[tt] + part2[tt + 64]; v2[tt] = vv; sqp = vv * vv; }
  }
  red[t] = sqp;
  __syncthreads();
  const int rbase = t & 128, ridx = t & 127;
  #pragma unroll
  for (int o = 64; o > 0; o >>= 1) {
    if (ridx < o) red[rbase + ridx] += red[rbase + ridx + o];
    __syncthreads();
  }
  const float dv1 = fmaxf(sqrtf(red[0]), EPSF);
  const float dv2 = fmaxf(sqrtf(red[128]), EPSF);
  __syncthreads();

  // phase C: g0: a1_i = (v1/dv1) @ W1m.T; g1: a2_i = (v2/dv2) @ W2m.T
  float sq2 = 0.0f;
  if (t < 128) {
    const int i = t >> 1, part = t & 1;
    const float4* wr = (const float4*)(w1 + (size_t)i * C_ + part * 256);
    float acc = 0.0f;
    #pragma unroll 8
    for (int q = 0; q < 64; q++) {
      float4 wv = wr[q];
      int j = part * 256 + 4 * q;
      acc += v1[j] * wv.x + v1[j + 1] * wv.y + v1[j + 2] * wv.z + v1[j + 3] * wv.w;
    }
    acc += __shfl_down(acc, 1);
    if (part == 0) { float a2 = acc / dv1; sq2 = a2 * a2; }
  } else {
    const int tt = t - 128;
    #pragma unroll
    for (int r = 0; r < 4; r++) {
      const int i = tt * 4 + r;
      const float4* wr = (const float4*)(w2 + (size_t)i * CR_);
      float acc = 0.0f;
      #pragma unroll
      for (int q = 0; q < 16; q++) {
        float4 wv = wr[q];
        acc += v2[4 * q] * wv.x + v2[4 * q + 1] * wv.y +
               v2[4 * q + 2] * wv.z + v2[4 * q + 3] * wv.w;
      }
      acc /= dv2;
      sq2 += acc * acc;
    }
  }
  red[t] = sq2;
  __syncthreads();
  #pragma unroll
  for (int o = 64; o > 0; o >>= 1) {
    if (ridx < o) red[rbase + ridx] += red[rbase + ridx + o];
    __syncthreads();
  }
  const float nt1 = red[0], nt2 = red[128];
  const float inv1 = fmaxf(sqrtf(nt1), EPSF) / nt1;   // 1/sv1
  const float inv2 = fmaxf(sqrtf(nt2), EPSF) / nt2;   // 1/sv2
  __syncthreads();

  // phase E: MLP
  if (t < 2 * CR_) {
    const int kind = t >> 6, i = t & 63;
    const float4* wr = (const float4*)(w1 + (size_t)i * C_);
    float acc = 0.0f;
    #pragma unroll 8
    for (int qq = 0; qq < C_ / 4; qq++) {
      float4 u = wr[qq];
      acc += pool2[kind][qq * 4 + 0] * u.x + pool2[kind][qq * 4 + 1] * u.y +
             pool2[kind][qq * 4 + 2] * u.z + pool2[kind][qq * 4 + 3] * u.w;
    }
    hid[kind][i] = fmaxf(acc * inv1 + b1[i], 0.0f);
  }
  __syncthreads();
  if (t < 128) {
    const int c = qtr * 128 + t;
    const float4* wr = (const float4*)(w2 + (size_t)c * CR_);
    float aa = 0.0f, mm = 0.0f;
    #pragma unroll
    for (int k = 0; k < 16; k++) {
      float4 wv = wr[k];
      aa += hid[0][4 * k] * wv.x + hid[0][4 * k + 1] * wv.y +
            hid[0][4 * k + 2] * wv.z + hid[0][4 * k + 3] * wv.w;
      mm += hid[1][4 * k] * wv.x + hid[1][4 * k + 1] * wv.y +
            hid[1][4 * k + 2] * wv.z + hid[1][4 * k + 3] * wv.w;
    }
    float val = (aa + mm) * inv2 + 2.0f * b2[c];
    s[b * C_ + c] = sigmoidf(val);
  }
}

// ---------------- K3: x*s, mean/max over C -> ca, cm ----------------
// grid dim3(16, B_), 1024 thr: lane = px-slot (64 float4 = 1 KB contiguous
// per channel per wave), wave = channel group (16 groups x 32 ch).
__global__ __launch_bounds__(1024) void scale_pool_kernel(const float* __restrict__ x,
                                                          const float* __restrict__ s,
                                                          float* __restrict__ ca,
                                                          float* __restrict__ cm) {
  const int b = blockIdx.y;
  const int px0 = blockIdx.x * 256;
  const int t = threadIdx.x;
  const int slot = t & 63;            // 64 float4 slots = 256 px
  const int cg = t >> 6;              // 16 groups * 32 channels
  __shared__ float srow[C_];
  for (int i = t; i < C_; i += 1024) srow[i] = s[b * C_ + i];
  __syncthreads();
  const float* xb = x + (size_t)b * C_ * HW_ + px0 + slot * 4;
  f32x4 sm = (f32x4)(0.f);
  f32x4 mxv = (f32x4)(-INFINITY);
  const int c0 = cg * 32;
  #pragma unroll 8
  for (int c = c0; c < c0 + 32; c++) {
    const f32x4 u = *(const f32x4*)(xb + (size_t)c * HW_);
    const f32x4 v = u * srow[c];
    sm += v;
    mxv.x = fmaxf(mxv.x, v.x); mxv.y = fmaxf(mxv.y, v.y);
    mxv.z = fmaxf(mxv.z, v.z); mxv.w = fmaxf(mxv.w, v.w);
  }
  __shared__ f32x4 rs[16][64], rm[16][64];  // 32 KB
  rs[cg][slot] = sm; rm[cg][slot] = mxv;
  __syncthreads();
  if (t < 64) {
    f32x4 S = rs[0][t], M = rm[0][t];
    #pragma unroll
    for (int g = 1; g < 16; g++) {
      const f32x4 a = rs[g][t], m2 = rm[g][t];
      S += a;
      M.x = fmaxf(M.x, m2.x); M.y = fmaxf(M.y, m2.y);
      M.z = fmaxf(M.z, m2.z); M.w = fmaxf(M.w, m2.w);
    }
    S *= (1.0f / C_);
    *(f32x4*)(ca + (size_t)b * HW_ + px0 + t * 4) = S;
    *(f32x4*)(cm + (size_t)b * HW_ + px0 + t * 4) = M;
  }
}

// ---------------- K4: conv(3x3, sv3) -> sy in LDS; out = x*s*sy ----------------
// grid dim3(16, B_), 1024 thr; block owns 256 px (4 rows) x all 512 channels.
// Same wave-contiguous mapping as K3; NT stores for out.
__global__ __launch_bounds__(1024) void conv_out_kernel(const float* __restrict__ x,
                                                        const float* __restrict__ s,
                                                        const float* __restrict__ ca,
                                                        const float* __restrict__ cm,
                                                        const float* __restrict__ w3,
                                                        const float* __restrict__ b3,
                                                        const float* __restrict__ u3,
                                                        float* __restrict__ out) {
  const int b = blockIdx.y;
  const int px0 = blockIdx.x * 256;
  const int t = threadIdx.x;
  __shared__ float srow[C_];
  __shared__ __align__(16) float syt[256];
  __shared__ float wns[18];
  __shared__ float b3s;
  if (t == 0) {
    float u3v = u3[0];
    float nvs = 0.0f;
    for (int k = 0; k < 18; k++) { float vv = u3v * w3[k]; nvs += vv * vv; }
    float d = fmaxf(sqrtf(nvs), EPSF);
    float tt = 0.0f;
    for (int k = 0; k < 18; k++) tt += (u3v * w3[k] / d) * w3[k];
    float u2n = tt / fmaxf(fabsf(tt), EPSF);
    float inv3 = 1.0f / (tt * u2n);
    for (int k = 0; k < 18; k++) wns[k] = w3[k] * inv3;
    b3s = b3[0];
  }
  for (int i = t; i < C_; i += 1024) srow[i] = s[b * C_ + i];
  __syncthreads();
  if (t < 256) {
    const int px = px0 + t;
    const int h = px >> 6, w = px & 63;
    float acc = b3s;
    #pragma unroll
    for (int dh = -1; dh <= 1; dh++) {
      int hh = h + dh;
      if (hh < 0 || hh >= 64) continue;
      #pragma unroll
      for (int dw = -1; dw <= 1; dw++) {
        int ww = w + dw;
        if (ww < 0 || ww >= WID_) continue;
        int n = b * HW_ + hh * WID_ + ww;
        int k = (dh + 1) * 3 + (dw + 1);
        acc += ca[n] * wns[k] + cm[n] * wns[9 + k];
      }
    }
    syt[t] = sigmoidf(acc);
  }
  __syncthreads();
  // stream phase: lane = px-slot (1 KB contiguous per channel per wave)
  const int slot = t & 63;
  const int cg = t >> 6;
  const f32x4 sy4 = *(const f32x4*)(&syt[slot * 4]);
  const size_t base = (size_t)b * C_ * HW_ + px0 + slot * 4;
  const int c0 = cg * 32;
  #pragma unroll 8
  for (int c = c0; c < c0 + 32; c++) {
    const f32x4 u = *(const f32x4*)(x + base + (size_t)c * HW_);
    const f32x4 r = u * (srow[c] * sy4);
    __builtin_nontemporal_store(r, (f32x4*)(out + base + (size_t)c * HW_));
  }
}

extern "C" void kernel_launch(void* const* d_in, const int* in_sizes, int n_in,
                              void* d_out, int out_size, void* d_ws, size_t ws_size,
                              hipStream_t stream) {
  const float* x  = (const float*)d_in[0];
  const float* w1 = (const float*)d_in[1];
  const float* b1 = (const float*)d_in[2];
  const float* u1 = (const float*)d_in[3];
  const float* w2 = (const float*)d_in[4];
  const float* b2 = (const float*)d_in[5];
  const float* u2 = (const float*)d_in[6];
  const float* w3 = (const float*)d_in[7];
  const float* b3 = (const float*)d_in[8];
  const float* u3 = (const float*)d_in[9];

  float* ws = (float*)d_ws;
  float* avg = ws;                    // 16384 floats
  float* mx  = ws + 16384;            // 16384
  float* s   = ws + 32768;            // 16384
  float* ca  = ws + 49152;            // 131072
  float* cm  = ws + 180224;           // 131072  (total ~1.2 MiB)

  pool_kernel<<<B_ * C_ / 4, 256, 0, stream>>>(x, avg, mx);
  mlp_kernel<<<dim3(4, B_), 256, 0, stream>>>(avg, mx, w1, b1, u1, w2, b2, u2, s);
  scale_pool_kernel<<<dim3(16, B_), 1024, 0, stream>>>(x, s, ca, cm);
  conv_out_kernel<<<dim3(16, B_), 1024, 0, stream>>>(x, s, ca, cm, w3, b3, u3, (float*)d_out);
}